// Round 11
// baseline (634.097 us; speedup 1.0000x reference)
//
#include <hip/hip_runtime.h>

typedef float f32x4 __attribute__((ext_vector_type(4)));
typedef unsigned int u32x2 __attribute__((ext_vector_type(2)));
typedef unsigned short u16x4 __attribute__((ext_vector_type(4)));
typedef __bf16 bf16x2 __attribute__((ext_vector_type(2)));
typedef __bf16 bf16x8 __attribute__((ext_vector_type(8)));

static_assert(sizeof(bf16x8) == 16, "bf16x8 must be 16B");

#define NB 4096
#define NT 64
#define NBLK 256
#define BTF (NB * NT * 64)   // 16777216

// Barrier draining ONLY lgkmcnt (LDS); global loads/stores stay in flight.
#define LGKM_BAR() do { \
    asm volatile("s_waitcnt lgkmcnt(0)" ::: "memory"); \
    __builtin_amdgcn_s_barrier(); \
  } while (0)

__device__ __forceinline__ unsigned short f2bf(float x) {
  return __builtin_bit_cast(unsigned short, (__bf16)x);
}
__device__ __forceinline__ unsigned int pk2(float lo, float hi) {
  bf16x2 t; t[0] = (__bf16)lo; t[1] = (__bf16)hi;
  return __builtin_bit_cast(unsigned int, t);
}
__device__ __forceinline__ float bf2f(unsigned int us) {   // low 16 bits -> f32
  return __builtin_bit_cast(float, us << 16);
}

__device__ __forceinline__ f32x4 mfma16(bf16x8 a, bf16x8 b, f32x4 c) {
  return __builtin_amdgcn_mfma_f32_16x16x32_bf16(a, b, c, 0, 0, 0);
}

__device__ __forceinline__ bf16x8 cvt8(f32x4 a, f32x4 b) {
  bf16x8 r;
#pragma unroll
  for (int j = 0; j < 4; ++j) { r[j] = (__bf16)a[j]; r[4 + j] = (__bf16)b[j]; }
  return r;
}

__device__ __forceinline__ bf16x8 loadW8(const float* __restrict__ row, int k0) {
  f32x4 a = *(const f32x4*)(row + k0);
  f32x4 b = *(const f32x4*)(row + k0 + 4);
  return cvt8(a, b);
}

__device__ __forceinline__ bf16x8 loadW8zd(const float* __restrict__ row, int k0, int col) {
  f32x4 a = *(const f32x4*)(row + k0);
  f32x4 b = *(const f32x4*)(row + k0 + 4);
  bf16x8 r;
#pragma unroll
  for (int j = 0; j < 4; ++j) {
    r[j]     = (k0 + j     == col) ? (__bf16)0.f : (__bf16)a[j];
    r[4 + j] = (k0 + 4 + j == col) ? (__bf16)0.f : (__bf16)b[j];
  }
  return r;
}

__device__ __forceinline__ float sigm(float x) { return 1.f / (1.f + __expf(-x)); }
__device__ __forceinline__ float tanh_fast(float x) { return 1.f - 2.f / (__expf(2.f * x) + 1.f); }

__device__ __forceinline__ f32x4 splat4(float v) { f32x4 r; r[0]=v; r[1]=v; r[2]=v; r[3]=v; return r; }

__global__ __launch_bounds__(1024, 1) void rits_main_kernel(
    const float* __restrict__ values, const float* __restrict__ masks,
    const float* __restrict__ deltas,
    const float* __restrict__ W_dh, const float* __restrict__ b_dh,
    const float* __restrict__ W_dx, const float* __restrict__ b_dx,
    const float* __restrict__ W_hist, const float* __restrict__ b_hist,
    const float* __restrict__ W_feat, const float* __restrict__ b_feat,
    const float* __restrict__ W_comb, const float* __restrict__ b_comb,
    const float* __restrict__ W_ih, const float* __restrict__ b_ih,
    const float* __restrict__ W_hh, const float* __restrict__ b_hh,
    float* __restrict__ out_imp, float* __restrict__ out_est,
    float* __restrict__ out_h, float* __restrict__ loss_ws) {
  const int tid = threadIdx.x;
  const int w = tid >> 6;              // wave 0..15
  const int l = tid & 63;
  const int rA = l & 15;               // MFMA A-row / C-col
  const int kg = l >> 4;               // k-group 0..3
  const int wg = blockIdx.x;
  const int b0 = wg * 16;
  const int colF = (w & 3) * 16 + rA;  // F-col (role GEMMs, w<8)
  const int colH = (w & 7) * 16 + rA;  // H-col (gate cols / state / twin)

  __shared__ float sX[2][16][68];
  __shared__ unsigned short sMb[2][16][72], sDb[2][16][72];
  __shared__ unsigned short sHb[2][16][136];
  __shared__ unsigned short sXcb[16][72], sCcb[16][72], sXhb[16][72], sZhb[16][72];
  __shared__ unsigned short sGxb[16][72];
  __shared__ float sCh[16][68], sCc[16][68];
  __shared__ float sGPT[512][20];          // twin gate partials [gatecol][row], padded
  __shared__ unsigned short sWh[64][136];  // W_hist bf16 [outcol][k]
  __shared__ unsigned short sWc[64][136];  // W_comb
  __shared__ unsigned short sWf[64][72];   // W_feat (diag zeroed)
  __shared__ float sWdxB[128];             // diag(W_dx) | b_dx
  __shared__ float sLoss[4][4];

  // ---------------- one-time init ----------------
  {
    int c = tid >> 4, k0 = (tid & 15) * 8;                 // 64 x 16 lanes
    *(bf16x8*)&sWh[c][k0] = loadW8(W_hist + (size_t)c * 128, k0);
    *(bf16x8*)&sWc[c][k0] = loadW8(W_comb + (size_t)c * 128, k0);
  }
  if (tid < 512) {
    int c = tid >> 3, k0 = (tid & 7) * 8;
    *(bf16x8*)&sWf[c][k0] = loadW8zd(W_feat + (size_t)c * 64, k0, c);
  }
  if (tid < 64)       sWdxB[tid] = W_dx[tid * 65];
  else if (tid < 128) sWdxB[tid] = b_dx[tid - 64];
  if (w < 8) {
#pragma unroll
    for (int i = 0; i < 4; ++i) sHb[0][kg * 4 + i][colH] = 0;
  }

  // ---------------- register weights (64 regs of gate frags per wave) ----------------
  bf16x8 wgf[4][4];
  if (w < 8) {
#pragma unroll
    for (int g = 0; g < 4; ++g) {
      int col = g * 128 + colH;
#pragma unroll
      for (int kk = 0; kk < 4; ++kk) wgf[g][kk] = loadW8(W_ih + (size_t)col * 128, kk * 32 + kg * 8);
    }
  } else {
#pragma unroll
    for (int g = 0; g < 4; ++g) {
      int col = g * 128 + colH;
#pragma unroll
      for (int kk = 0; kk < 4; ++kk) wgf[g][kk] = loadW8(W_hh + (size_t)col * 128, kk * 32 + kg * 8);
    }
  }
  bf16x8 wdhf[2];
  if (w < 8) {
#pragma unroll
    for (int kk = 0; kk < 2; ++kk) wdhf[kk] = loadW8(W_dh + (size_t)colH * 64, kk * 32 + kg * 8);
  } else {
    bf16x8 z = {}; wdhf[0] = z; wdhf[1] = z;
  }

  float bg[4] = {0.f, 0.f, 0.f, 0.f};
  float bdh = 0.f, bhist = 0.f, bcomb = 0.f, bfeat = 0.f;
  if (w < 8) {
#pragma unroll
    for (int g = 0; g < 4; ++g) bg[g] = b_ih[g * 128 + colH] + b_hh[g * 128 + colH];
    bdh = b_dh[colH];
    if (w < 4) bhist = b_hist[colF];
    else       { bcomb = b_comb[colF]; bfeat = b_feat[colF]; }
  }

  f32x4 h_reg = {0.f, 0.f, 0.f, 0.f};
  f32x4 c_reg = {0.f, 0.f, 0.f, 0.f};

  // staging lanes: waves 8-11
  const int sidx = tid - 512;                       // valid when 0<=sidx<256
  const int ssr = (sidx & 255) >> 4, ssq = sidx & 15;
  const size_t gbase = (size_t)(b0 + ssr) * 4096 + ssq * 4;
  // loss lanes: waves 8-11 reuse ssr/ssq. store lanes: waves 12-15
  const int oidx = tid - 768;
  const int orow = (oidx & 255) >> 4, oq = oidx & 15;
  float* pE = out_est + (size_t)(b0 + orow) * 4096 + oq * 4;
  float* pI = out_imp + (size_t)(b0 + orow) * 4096 + oq * 4;

  // ---------------- prologue ----------------
  f32x4 vx, vm, vd;
  if (w >= 8 && w < 12) {
    f32x4 vx0 = *(const f32x4*)&values[gbase];
    f32x4 vm0 = *(const f32x4*)&masks[gbase];
    f32x4 vd0 = *(const f32x4*)&deltas[gbase];
    *(f32x4*)&sX[0][ssr][ssq * 4] = vx0;
    u32x2 pm, pd;
    pm[0] = pk2(vm0[0], vm0[1]); pm[1] = pk2(vm0[2], vm0[3]);
    pd[0] = pk2(vd0[0], vd0[1]); pd[1] = pk2(vd0[2], vd0[3]);
    *(u32x2*)&sMb[0][ssr][ssq * 4] = pm;
    *(u32x2*)&sDb[0][ssr][ssq * 4] = pd;
  }
  LGKM_BAR();
  if (tid < 256) {   // gamma_x(0): 4 elems/thread
    int row = tid >> 4, f0 = (tid & 15) * 4;
    u32x2 dp = *(const u32x2*)&sDb[0][row][f0];
    float g0 = __expf(-fmaxf(bf2f(dp[0] & 0xffffu) * sWdxB[f0]     + sWdxB[64 + f0],     0.f));
    float g1 = __expf(-fmaxf(bf2f(dp[0] >> 16)     * sWdxB[f0 + 1] + sWdxB[64 + f0 + 1], 0.f));
    float g2 = __expf(-fmaxf(bf2f(dp[1] & 0xffffu) * sWdxB[f0 + 2] + sWdxB[64 + f0 + 2], 0.f));
    float g3 = __expf(-fmaxf(bf2f(dp[1] >> 16)     * sWdxB[f0 + 3] + sWdxB[64 + f0 + 3], 0.f));
    u32x2 gp; gp[0] = pk2(g0, g1); gp[1] = pk2(g2, g3);
    *(u32x2*)&sGxb[row][f0] = gp;
  }
  if (w >= 8 && w < 12) {
    vx = *(const f32x4*)&values[gbase + 64];
    vm = *(const f32x4*)&masks[gbase + 64];
    vd = *(const f32x4*)&deltas[gbase + 64];
  }
  LGKM_BAR();

  // ---------------- time loop: 3 lgkm-only barriers per step ----------------
  for (int t = 0; t < NT; ++t) {
    const int p = t & 1;
    f32x4 acc[4];
    f32x4 alpha_r = {0.f, 0.f, 0.f, 0.f};

    // ========== P1 ==========
    if (t > 0 && tid < 4) {
      float lsv = sLoss[0][tid] + sLoss[1][tid] + sLoss[2][tid] + sLoss[3][tid];
      loss_ws[((size_t)(t - 1) * NBLK + wg) * 4 + tid] = lsv;
    }
    if (w < 8) {
      // stable m-chunk gate MFMAs (8), acc init with fused bias
#pragma unroll
      for (int g = 0; g < 4; ++g) acc[g] = splat4(bg[g]);
      bf16x8 am0 = *(const bf16x8*)&sMb[p][rA][kg * 8];
      bf16x8 am1 = *(const bf16x8*)&sMb[p][rA][32 + kg * 8];
#pragma unroll
      for (int g = 0; g < 4; ++g) acc[g] = mfma16(am0, wgf[g][2], acc[g]);
#pragma unroll
      for (int g = 0; g < 4; ++g) acc[g] = mfma16(am1, wgf[g][3], acc[g]);
      if (w < 4) {
        // x_h GEMM (B-frags from LDS W_hist)
        f32x4 axh = splat4(bhist);
#pragma unroll
        for (int kk = 0; kk < 4; ++kk) {
          bf16x8 a = *(const bf16x8*)&sHb[p][rA][kk * 32 + kg * 8];
          bf16x8 b = *(const bf16x8*)&sWh[colF][kk * 32 + kg * 8];
          axh = mfma16(a, b, axh);
        }
#pragma unroll
        for (int i = 0; i < 4; ++i) {
          int row = kg * 4 + i;
          float xh = axh[i];
          float xr = sX[p][row][colF];
          float mr = bf2f(sMb[p][row][colF]);
          float xc = mr * xr + (1.f - mr) * xh;
          sXcb[row][colF] = f2bf(xc);
          sXhb[row][colF] = f2bf(xh);
        }
      } else {
        // alpha GEMM (B from LDS W_comb; A: gamma_x + m frags)
        f32x4 aal = splat4(bcomb);
        bf16x8 gx0 = *(const bf16x8*)&sGxb[rA][kg * 8];
        bf16x8 gx1 = *(const bf16x8*)&sGxb[rA][32 + kg * 8];
        aal = mfma16(gx0, *(const bf16x8*)&sWc[colF][kg * 8], aal);
        aal = mfma16(gx1, *(const bf16x8*)&sWc[colF][32 + kg * 8], aal);
        aal = mfma16(am0, *(const bf16x8*)&sWc[colF][64 + kg * 8], aal);
        aal = mfma16(am1, *(const bf16x8*)&sWc[colF][96 + kg * 8], aal);
#pragma unroll
        for (int i = 0; i < 4; ++i) alpha_r[i] = sigm(aal[i]);
      }
    } else {
      // twin: 16 h~ gate MFMAs -> partial to sGPT
      f32x4 at[4];
#pragma unroll
      for (int g = 0; g < 4; ++g) { f32x4 z = {0.f, 0.f, 0.f, 0.f}; at[g] = z; }
      bf16x8 ah[4];
#pragma unroll
      for (int kk = 0; kk < 4; ++kk) ah[kk] = *(const bf16x8*)&sHb[p][rA][kk * 32 + kg * 8];
#pragma unroll
      for (int kk = 0; kk < 4; ++kk)
#pragma unroll
        for (int g = 0; g < 4; ++g) at[g] = mfma16(ah[kk], wgf[g][kk], at[g]);
#pragma unroll
      for (int g = 0; g < 4; ++g) *(f32x4*)&sGPT[g * 128 + colH][kg * 4] = at[g];
      if (w < 12) {
        // staging writes of t+1 (vmcnt wait lands here)
        *(f32x4*)&sX[p ^ 1][ssr][ssq * 4] = vx;
        u32x2 pm, pd;
        pm[0] = pk2(vm[0], vm[1]); pm[1] = pk2(vm[2], vm[3]);
        pd[0] = pk2(vd[0], vd[1]); pd[1] = pk2(vd[2], vd[3]);
        *(u32x2*)&sMb[p ^ 1][ssr][ssq * 4] = pm;
        *(u32x2*)&sDb[p ^ 1][ssr][ssq * 4] = pd;
      }
    }
    LGKM_BAR();   // bar A

    // ========== P2 ==========
    if (w < 8) {
      // fold in twin partial
#pragma unroll
      for (int g = 0; g < 4; ++g) acc[g] += *(const f32x4*)&sGPT[g * 128 + colH][kg * 4];
    }
    if (w >= 4 && w < 8) {
      // z_h + imputation epilogue (alpha in-register)
      f32x4 az = splat4(bfeat);
      bf16x8 ax0 = *(const bf16x8*)&sXcb[rA][kg * 8];
      bf16x8 ax1 = *(const bf16x8*)&sXcb[rA][32 + kg * 8];
      az = mfma16(ax0, *(const bf16x8*)&sWf[colF][kg * 8], az);
      az = mfma16(ax1, *(const bf16x8*)&sWf[colF][32 + kg * 8], az);
#pragma unroll
      for (int i = 0; i < 4; ++i) {
        int row = kg * 4 + i;
        float zh = az[i];
        float xh = bf2f(sXhb[row][colF]);
        float al = alpha_r[i];
        float ch = al * zh + (1.f - al) * xh;
        float xr = sX[p][row][colF];
        float mr = bf2f(sMb[p][row][colF]);
        float cc = mr * xr + (1.f - mr) * ch;
        sCh[row][colF] = ch;
        sCc[row][colF] = cc;
        sCcb[row][colF] = f2bf(cc);
        sZhb[row][colF] = f2bf(zh);
      }
    } else if (w < 4) {
      // gamma_x(t+1): 4 elems/thread (tid<256)
      int row = tid >> 4, f0 = (tid & 15) * 4;
      u32x2 dp = *(const u32x2*)&sDb[p ^ 1][row][f0];
      float g0 = __expf(-fmaxf(bf2f(dp[0] & 0xffffu) * sWdxB[f0]     + sWdxB[64 + f0],     0.f));
      float g1 = __expf(-fmaxf(bf2f(dp[0] >> 16)     * sWdxB[f0 + 1] + sWdxB[64 + f0 + 1], 0.f));
      float g2 = __expf(-fmaxf(bf2f(dp[1] & 0xffffu) * sWdxB[f0 + 2] + sWdxB[64 + f0 + 2], 0.f));
      float g3 = __expf(-fmaxf(bf2f(dp[1] >> 16)     * sWdxB[f0 + 3] + sWdxB[64 + f0 + 3], 0.f));
      u32x2 gp; gp[0] = pk2(g0, g1); gp[1] = pk2(g2, g3);
      *(u32x2*)&sGxb[row][f0] = gp;
    }
    LGKM_BAR();   // bar B

    // ========== E ==========
    if (w >= 12) {
      // est/imp coalesced stores
      *(f32x4*)pE = *(const f32x4*)&sCh[orow][oq * 4];
      *(f32x4*)pI = *(const f32x4*)&sCc[orow][oq * 4];
      pE += 64; pI += 64;
    } else if (w >= 8) {
      // issue t+2 loads, then loss for step t
      int tq = (t + 2 <= NT - 1) ? t + 2 : NT - 1;
      size_t ga = gbase + (size_t)(tq << 6);
      vx = *(const f32x4*)&values[ga];
      vm = *(const f32x4*)&masks[ga];
      vd = *(const f32x4*)&deltas[ga];
      f32x4 xv = *(const f32x4*)&sX[p][ssr][ssq * 4];
      f32x4 chv = *(const f32x4*)&sCh[ssr][ssq * 4];
      u16x4 mv = *(const u16x4*)&sMb[p][ssr][ssq * 4];
      u16x4 xhv = *(const u16x4*)&sXhb[ssr][ssq * 4];
      u16x4 zhv = *(const u16x4*)&sZhb[ssr][ssq * 4];
      float n1 = 0.f, n2 = 0.f, n3 = 0.f, den = 0.f;
#pragma unroll
      for (int j = 0; j < 4; ++j) {
        float m = bf2f(mv[j]);
        float x = xv[j];
        n1 += fabsf(bf2f(xhv[j]) - x) * m;
        n2 += fabsf(bf2f(zhv[j]) - x) * m;
        n3 += fabsf(chv[j] - x) * m;
        den += m;
      }
#pragma unroll
      for (int off = 32; off > 0; off >>= 1) {
        n1 += __shfl_down(n1, off);
        n2 += __shfl_down(n2, off);
        n3 += __shfl_down(n3, off);
        den += __shfl_down(den, off);
      }
      if (l == 0) {
        f32x4 lv; lv[0] = n1; lv[1] = n2; lv[2] = n3; lv[3] = den;
        *(f32x4*)&sLoss[w - 8][0] = lv;
      }
    }
    if (w < 8) {
      // fresh c_c gate MFMAs (8) + LSTM + gamma_h(t+1)
      bf16x8 ac0 = *(const bf16x8*)&sCcb[rA][kg * 8];
      bf16x8 ac1 = *(const bf16x8*)&sCcb[rA][32 + kg * 8];
#pragma unroll
      for (int g = 0; g < 4; ++g) acc[g] = mfma16(ac0, wgf[g][0], acc[g]);
#pragma unroll
      for (int g = 0; g < 4; ++g) acc[g] = mfma16(ac1, wgf[g][1], acc[g]);
#pragma unroll
      for (int i = 0; i < 4; ++i) {
        float ii = sigm(acc[0][i]);
        float ff = sigm(acc[1][i]);
        float g_ = tanh_fast(acc[2][i]);
        float oo = sigm(acc[3][i]);
        float c_ = ff * c_reg[i] + ii * g_;
        c_reg[i] = c_;
        h_reg[i] = oo * tanh_fast(c_);
      }
      if (t < NT - 1) {
        f32x4 ga4 = splat4(bdh);
        bf16x8 a0 = *(const bf16x8*)&sDb[p ^ 1][rA][kg * 8];
        bf16x8 a1 = *(const bf16x8*)&sDb[p ^ 1][rA][32 + kg * 8];
        ga4 = mfma16(a0, wdhf[0], ga4);
        ga4 = mfma16(a1, wdhf[1], ga4);
#pragma unroll
        for (int i = 0; i < 4; ++i) {
          float g = __expf(-fmaxf(ga4[i], 0.f));
          h_reg[i] *= g;
          sHb[p ^ 1][kg * 4 + i][colH] = f2bf(h_reg[i]);
        }
      } else {
#pragma unroll
        for (int i = 0; i < 4; ++i) out_h[(size_t)(b0 + kg * 4 + i) * 128 + colH] = h_reg[i];
      }
    }
    LGKM_BAR();   // bar C
  }

  // final loss_ws writeback for t = NT-1
  if (tid < 4) {
    float lsv = sLoss[0][tid] + sLoss[1][tid] + sLoss[2][tid] + sLoss[3][tid];
    loss_ws[((size_t)(NT - 1) * NBLK + wg) * 4 + tid] = lsv;
  }
}

__global__ void rits_loss_kernel(const float* __restrict__ ws, float* __restrict__ out_loss) {
  int tid = threadIdx.x;  // 64 threads; thread t handles step t
  float n1 = 0.f, n2 = 0.f, n3 = 0.f, den = 0.f;
  for (int g = 0; g < NBLK; ++g) {
    const float* p = &ws[((size_t)tid * NBLK + g) * 4];
    n1 += p[0]; n2 += p[1]; n3 += p[2]; den += p[3];
  }
  float lt = (n1 + n2 + n3) / (den + 1e-12f);
#pragma unroll
  for (int off = 32; off > 0; off >>= 1) lt += __shfl_down(lt, off);
  if (tid == 0) out_loss[0] = lt / 192.f;   // / (T * 3)
}

extern "C" void kernel_launch(void* const* d_in, const int* in_sizes, int n_in,
                              void* d_out, int out_size, void* d_ws, size_t ws_size,
                              hipStream_t stream) {
  const float* values = (const float*)d_in[0];
  const float* masks  = (const float*)d_in[1];
  const float* deltas = (const float*)d_in[2];
  const float* W_dh   = (const float*)d_in[3];
  const float* b_dh   = (const float*)d_in[4];
  const float* W_dx   = (const float*)d_in[5];
  const float* b_dx   = (const float*)d_in[6];
  const float* W_hist = (const float*)d_in[7];
  const float* b_hist = (const float*)d_in[8];
  const float* W_feat = (const float*)d_in[9];
  const float* b_feat = (const float*)d_in[10];
  const float* W_comb = (const float*)d_in[11];
  const float* b_comb = (const float*)d_in[12];
  const float* W_ih   = (const float*)d_in[13];
  const float* b_ih   = (const float*)d_in[14];
  const float* W_hh   = (const float*)d_in[15];
  const float* b_hh   = (const float*)d_in[16];

  float* out = (float*)d_out;
  float* out_imp = out;                       // [B,T,F]
  float* out_est = out + (size_t)BTF;         // [B,T,F]
  float* out_h   = out + (size_t)2 * BTF;     // [B,H]
  float* out_ls  = out + (size_t)2 * BTF + (size_t)NB * 128;  // scalar
  float* loss_ws = (float*)d_ws;              // [T][NBLK][4]

  rits_main_kernel<<<NBLK, 1024, 0, stream>>>(
      values, masks, deltas, W_dh, b_dh, W_dx, b_dx, W_hist, b_hist,
      W_feat, b_feat, W_comb, b_comb, W_ih, b_ih, W_hh, b_hh,
      out_imp, out_est, out_h, loss_ws);
  rits_loss_kernel<<<1, 64, 0, stream>>>(loss_ws, out_ls);
}

// Round 12
// 559.364 us; speedup vs baseline: 1.1336x; 1.1336x over previous
//
#include <hip/hip_runtime.h>

typedef float f32x4 __attribute__((ext_vector_type(4)));
typedef unsigned int u32x2 __attribute__((ext_vector_type(2)));
typedef unsigned short u16x4 __attribute__((ext_vector_type(4)));
typedef __bf16 bf16x2 __attribute__((ext_vector_type(2)));
typedef __bf16 bf16x8 __attribute__((ext_vector_type(8)));

static_assert(sizeof(bf16x8) == 16, "bf16x8 must be 16B");

#define NB 4096
#define NT 64
#define NBLK 256
#define BTF (NB * NT * 64)   // 16777216

// Barrier draining ONLY lgkmcnt (LDS); global loads/stores stay in flight.
#define LGKM_BAR() do { \
    asm volatile("s_waitcnt lgkmcnt(0)" ::: "memory"); \
    __builtin_amdgcn_s_barrier(); \
  } while (0)

__device__ __forceinline__ unsigned short f2bf(float x) {
  return __builtin_bit_cast(unsigned short, (__bf16)x);
}
__device__ __forceinline__ unsigned int pk2(float lo, float hi) {
  bf16x2 t; t[0] = (__bf16)lo; t[1] = (__bf16)hi;
  return __builtin_bit_cast(unsigned int, t);
}
__device__ __forceinline__ float bf2f(unsigned int us) {   // low 16 bits -> f32
  return __builtin_bit_cast(float, us << 16);
}

__device__ __forceinline__ f32x4 mfma16(bf16x8 a, bf16x8 b, f32x4 c) {
  return __builtin_amdgcn_mfma_f32_16x16x32_bf16(a, b, c, 0, 0, 0);
}

__device__ __forceinline__ bf16x8 cvt8(f32x4 a, f32x4 b) {
  bf16x8 r;
#pragma unroll
  for (int j = 0; j < 4; ++j) { r[j] = (__bf16)a[j]; r[4 + j] = (__bf16)b[j]; }
  return r;
}

__device__ __forceinline__ bf16x8 loadW8(const float* __restrict__ row, int k0) {
  f32x4 a = *(const f32x4*)(row + k0);
  f32x4 b = *(const f32x4*)(row + k0 + 4);
  return cvt8(a, b);
}

__device__ __forceinline__ bf16x8 loadW8zd(const float* __restrict__ row, int k0, int col) {
  f32x4 a = *(const f32x4*)(row + k0);
  f32x4 b = *(const f32x4*)(row + k0 + 4);
  bf16x8 r;
#pragma unroll
  for (int j = 0; j < 4; ++j) {
    r[j]     = (k0 + j     == col) ? (__bf16)0.f : (__bf16)a[j];
    r[4 + j] = (k0 + 4 + j == col) ? (__bf16)0.f : (__bf16)b[j];
  }
  return r;
}

__device__ __forceinline__ float sigm(float x) { return 1.f / (1.f + __expf(-x)); }
__device__ __forceinline__ float tanh_fast(float x) { return 1.f - 2.f / (__expf(2.f * x) + 1.f); }
__device__ __forceinline__ f32x4 splat4(float v) { f32x4 r; r[0]=v; r[1]=v; r[2]=v; r[3]=v; return r; }

__global__ __launch_bounds__(768, 3) void rits_main_kernel(
    const float* __restrict__ values, const float* __restrict__ masks,
    const float* __restrict__ deltas,
    const float* __restrict__ W_dh, const float* __restrict__ b_dh,
    const float* __restrict__ W_dx, const float* __restrict__ b_dx,
    const float* __restrict__ W_hist, const float* __restrict__ b_hist,
    const float* __restrict__ W_feat, const float* __restrict__ b_feat,
    const float* __restrict__ W_comb, const float* __restrict__ b_comb,
    const float* __restrict__ W_ih, const float* __restrict__ b_ih,
    const float* __restrict__ W_hh, const float* __restrict__ b_hh,
    float* __restrict__ out_imp, float* __restrict__ out_est,
    float* __restrict__ out_h, float* __restrict__ loss_ws) {
  const int tid = threadIdx.x;
  const int w = tid >> 6;              // 0..11: w<8 owners, w>=8 twins
  const int l = tid & 63;
  const int rA = l & 15;               // MFMA A-row / C-col
  const int kg = l >> 4;               // k-group 0..3
  const int wg = blockIdx.x;
  const int b0 = wg * 16;
  const int colH = (w & 7) * 16 + rA;  // owner H-col 0..127
  const int colF = (w & 3) * 16 + rA;  // F-col 0..63
  const int sidx = tid & 255;          // 256-lane work index (per role group)
  const int srow = sidx >> 4, sq = sidx & 15;
  const size_t gb = (size_t)(b0 + srow) * 4096 + sq * 4;  // unified elem base

  __shared__ float sX[2][16][68];
  __shared__ unsigned short sMb[2][16][72], sDb[2][16][72];
  __shared__ unsigned short sHb[2][16][136];
  __shared__ unsigned short sXcb[16][72], sCcb[16][72], sXhb[16][72], sZhb[16][72];
  __shared__ unsigned short sGxb[16][72];
  __shared__ float sAlT[64][20];            // alpha transposed [col][row]
  __shared__ float sCh[16][68], sCc[16][68];
  __shared__ float sGPT[512][17];           // twin gate partials [gatecol][row]
  __shared__ unsigned short sWh[64][136];   // W_hist bf16 [outcol][k]
  __shared__ unsigned short sWc[64][136];   // W_comb
  __shared__ unsigned short sWf[64][72];    // W_feat (diag zeroed)
  __shared__ float sWdxB[128];              // diag(W_dx) | b_dx
  __shared__ float sBg[512];                // b_ih + b_hh
  __shared__ float sB[320];                 // bhist|bfeat|bcomb|bdh
  __shared__ float sLoss[4][4];

  // ---------------- one-time init ----------------
  if (tid < 512) {
    int c = tid >> 3, k0 = (tid & 7) * 16;
    const float* wrh = W_hist + (size_t)c * 128 + k0;
    const float* wrc = W_comb + (size_t)c * 128 + k0;
    *(bf16x8*)&sWh[c][k0]     = loadW8(wrh, 0);
    *(bf16x8*)&sWh[c][k0 + 8] = loadW8(wrh, 8);
    *(bf16x8*)&sWc[c][k0]     = loadW8(wrc, 0);
    *(bf16x8*)&sWc[c][k0 + 8] = loadW8(wrc, 8);
    int kf = (tid & 7) * 8;
    *(bf16x8*)&sWf[c][kf] = loadW8zd(W_feat + (size_t)c * 64, kf, c);
    sBg[tid] = b_ih[tid] + b_hh[tid];
  }
  if (tid < 64)       sWdxB[tid] = W_dx[tid * 65];
  else if (tid < 128) sWdxB[tid] = b_dx[tid - 64];
  if (tid >= 512 && tid < 512 + 320) {
    int i = tid - 512;
    float v;
    if (i < 64)       v = b_hist[i];
    else if (i < 128) v = b_feat[i - 64];
    else if (i < 192) v = b_comb[i - 128];
    else              v = b_dh[i - 192];
    sB[i] = v;
  }
  if (w < 8) {
#pragma unroll
    for (int i = 0; i < 4; ++i) sHb[0][kg * 4 + i][colH] = 0;
  }

  // ------- unified weight fragments (roles share the SAME virtual regs) -------
  // owners: [g*5+0..1]=W_ih cc, [g*5+2..3]=W_ih m, [g*5+4]=W_hh k96-127, [20..21]=W_dh
  // twins:  [s*12+g*3+kk] = W_hh k(kk*32..) for col-set (2*(w-8)+s)
  bf16x8 wga[24];
  if (w < 8) {
#pragma unroll
    for (int g = 0; g < 4; ++g) {
      const float* wr_ih = W_ih + (size_t)(g * 128 + colH) * 128;
      const float* wr_hh = W_hh + (size_t)(g * 128 + colH) * 128;
#pragma unroll
      for (int kk = 0; kk < 4; ++kk) wga[g * 5 + kk] = loadW8(wr_ih, kk * 32 + kg * 8);
      wga[g * 5 + 4] = loadW8(wr_hh, 96 + kg * 8);
    }
    wga[20] = loadW8(W_dh + (size_t)colH * 64, kg * 8);
    wga[21] = loadW8(W_dh + (size_t)colH * 64, 32 + kg * 8);
    { bf16x8 z = {}; wga[22] = z; wga[23] = z; }
  } else {
#pragma unroll
    for (int s = 0; s < 2; ++s) {
      int cset = (2 * (w - 8) + s) * 16 + rA;
#pragma unroll
      for (int g = 0; g < 4; ++g) {
        const float* wr = W_hh + (size_t)(g * 128 + cset) * 128;
#pragma unroll
        for (int kk = 0; kk < 3; ++kk) wga[s * 12 + g * 3 + kk] = loadW8(wr, kk * 32 + kg * 8);
      }
    }
  }

  f32x4 h_reg = {0.f, 0.f, 0.f, 0.f};
  f32x4 c_reg = {0.f, 0.f, 0.f, 0.f};

  // ---------------- prologue ----------------
  f32x4 vx, vm, vd;
  if (w >= 8) {
    f32x4 vx0 = *(const f32x4*)&values[gb];
    f32x4 vm0 = *(const f32x4*)&masks[gb];
    f32x4 vd0 = *(const f32x4*)&deltas[gb];
    *(f32x4*)&sX[0][srow][sq * 4] = vx0;
    u32x2 pm, pd;
    pm[0] = pk2(vm0[0], vm0[1]); pm[1] = pk2(vm0[2], vm0[3]);
    pd[0] = pk2(vd0[0], vd0[1]); pd[1] = pk2(vd0[2], vd0[3]);
    *(u32x2*)&sMb[0][srow][sq * 4] = pm;
    *(u32x2*)&sDb[0][srow][sq * 4] = pd;
  }
  LGKM_BAR();
  if (w >= 4 && w < 8) {   // gamma_x(0): 256 lanes x 4 elems
    int f0 = sq * 4;
    u32x2 dp = *(const u32x2*)&sDb[0][srow][f0];
    float g0 = __expf(-fmaxf(bf2f(dp[0] & 0xffffu) * sWdxB[f0]     + sWdxB[64 + f0],     0.f));
    float g1 = __expf(-fmaxf(bf2f(dp[0] >> 16)     * sWdxB[f0 + 1] + sWdxB[64 + f0 + 1], 0.f));
    float g2 = __expf(-fmaxf(bf2f(dp[1] & 0xffffu) * sWdxB[f0 + 2] + sWdxB[64 + f0 + 2], 0.f));
    float g3 = __expf(-fmaxf(bf2f(dp[1] >> 16)     * sWdxB[f0 + 3] + sWdxB[64 + f0 + 3], 0.f));
    u32x2 gp; gp[0] = pk2(g0, g1); gp[1] = pk2(g2, g3);
    *(u32x2*)&sGxb[srow][f0] = gp;
  }
  if (w >= 8) {   // issue t=1 loads
    vx = *(const f32x4*)&values[gb + 64];
    vm = *(const f32x4*)&masks[gb + 64];
    vd = *(const f32x4*)&deltas[gb + 64];
  }
  LGKM_BAR();

  // ---------------- time loop: 3 lgkm-only barriers per step ----------------
  for (int t = 0; t < NT; ++t) {
    const int p = t & 1;

    // ========== P1 ==========
    if (t > 0 && tid < 4) {
      float lsv = sLoss[0][tid] + sLoss[1][tid] + sLoss[2][tid] + sLoss[3][tid];
      loss_ws[((size_t)(t - 1) * NBLK + wg) * 4 + tid] = lsv;
    }
    if (w < 4) {
      // x_h GEMM (B from LDS W_hist)
      f32x4 axh = splat4(sB[colF]);
#pragma unroll
      for (int kk = 0; kk < 4; ++kk) {
        bf16x8 a = *(const bf16x8*)&sHb[p][rA][kk * 32 + kg * 8];
        bf16x8 b = *(const bf16x8*)&sWh[colF][kk * 32 + kg * 8];
        axh = mfma16(a, b, axh);
      }
#pragma unroll
      for (int i = 0; i < 4; ++i) {
        int row = kg * 4 + i;
        float xr = sX[p][row][colF];
        float mr = bf2f(sMb[p][row][colF]);
        float xc = mr * xr + (1.f - mr) * axh[i];
        sXcb[row][colF] = f2bf(xc);
        sXhb[row][colF] = f2bf(axh[i]);
      }
    } else if (w < 8) {
      // alpha GEMM (B from LDS W_comb)
      f32x4 aal = splat4(sB[128 + colF]);
      bf16x8 gx0 = *(const bf16x8*)&sGxb[rA][kg * 8];
      bf16x8 gx1 = *(const bf16x8*)&sGxb[rA][32 + kg * 8];
      bf16x8 m0  = *(const bf16x8*)&sMb[p][rA][kg * 8];
      bf16x8 m1  = *(const bf16x8*)&sMb[p][rA][32 + kg * 8];
      aal = mfma16(gx0, *(const bf16x8*)&sWc[colF][kg * 8], aal);
      aal = mfma16(gx1, *(const bf16x8*)&sWc[colF][32 + kg * 8], aal);
      aal = mfma16(m0,  *(const bf16x8*)&sWc[colF][64 + kg * 8], aal);
      aal = mfma16(m1,  *(const bf16x8*)&sWc[colF][96 + kg * 8], aal);
      f32x4 alv;
#pragma unroll
      for (int i = 0; i < 4; ++i) alv[i] = sigm(aal[i]);
      *(f32x4*)&sAlT[colF][kg * 4] = alv;
    } else {
      // twins: h~ k0-95 gate partials for 2 col-sets
      bf16x8 ah0 = *(const bf16x8*)&sHb[p][rA][kg * 8];
      bf16x8 ah1 = *(const bf16x8*)&sHb[p][rA][32 + kg * 8];
      bf16x8 ah2 = *(const bf16x8*)&sHb[p][rA][64 + kg * 8];
#pragma unroll
      for (int s = 0; s < 2; ++s) {
        int cset = (2 * (w - 8) + s) * 16 + rA;
#pragma unroll
        for (int g = 0; g < 4; ++g) {
          f32x4 at = {0.f, 0.f, 0.f, 0.f};
          at = mfma16(ah0, wga[s * 12 + g * 3 + 0], at);
          at = mfma16(ah1, wga[s * 12 + g * 3 + 1], at);
          at = mfma16(ah2, wga[s * 12 + g * 3 + 2], at);
          *(f32x4*)&sGPT[g * 128 + cset][kg * 4] = at;
        }
      }
    }
    LGKM_BAR();   // bar A: sXcb/sXhb/sAlT/sGPT ready

    // ========== P3 ==========
    f32x4 acc[4];
    if (w < 8) {
      // stable gate MFMAs: m (k128-255 of W_ih-layout) + h~ k96-127
      bf16x8 am0 = *(const bf16x8*)&sMb[p][rA][kg * 8];
      bf16x8 am1 = *(const bf16x8*)&sMb[p][rA][32 + kg * 8];
      bf16x8 ah3 = *(const bf16x8*)&sHb[p][rA][96 + kg * 8];
#pragma unroll
      for (int g = 0; g < 4; ++g) {
        acc[g] = splat4(sBg[g * 128 + colH]);
        acc[g] = mfma16(am0, wga[g * 5 + 2], acc[g]);
        acc[g] = mfma16(am1, wga[g * 5 + 3], acc[g]);
        acc[g] = mfma16(ah3, wga[g * 5 + 4], acc[g]);
      }
    }
    if (w >= 4 && w < 8) {
      // z_h GEMM + imputation epilogue
      f32x4 az = splat4(sB[64 + colF]);
      bf16x8 ax0 = *(const bf16x8*)&sXcb[rA][kg * 8];
      bf16x8 ax1 = *(const bf16x8*)&sXcb[rA][32 + kg * 8];
      az = mfma16(ax0, *(const bf16x8*)&sWf[colF][kg * 8], az);
      az = mfma16(ax1, *(const bf16x8*)&sWf[colF][32 + kg * 8], az);
      f32x4 alv = *(const f32x4*)&sAlT[colF][kg * 4];
#pragma unroll
      for (int i = 0; i < 4; ++i) {
        int row = kg * 4 + i;
        float zh = az[i];
        float xh = bf2f(sXhb[row][colF]);
        float al = alv[i];
        float ch = al * zh + (1.f - al) * xh;
        float xr = sX[p][row][colF];
        float mr = bf2f(sMb[p][row][colF]);
        float cc = mr * xr + (1.f - mr) * ch;
        sCh[row][colF] = ch;
        sCc[row][colF] = cc;
        sCcb[row][colF] = f2bf(cc);
        sZhb[row][colF] = f2bf(zh);
      }
    } else if (w >= 8) {
      // staging writes of t+1 (vmcnt wait for vx/vm/vd lands here)
      *(f32x4*)&sX[p ^ 1][srow][sq * 4] = vx;
      u32x2 pm, pd;
      pm[0] = pk2(vm[0], vm[1]); pm[1] = pk2(vm[2], vm[3]);
      pd[0] = pk2(vd[0], vd[1]); pd[1] = pk2(vd[2], vd[3]);
      *(u32x2*)&sMb[p ^ 1][srow][sq * 4] = pm;
      *(u32x2*)&sDb[p ^ 1][srow][sq * 4] = pd;
    }
    LGKM_BAR();   // bar B: sCcb/sCh/sCc/sZhb + staged t+1 ready

    // ========== E ==========
    if (w < 8) {
      // fresh c_c gates + twin-partial fold + LSTM + gamma_h(t+1)
      bf16x8 ac0 = *(const bf16x8*)&sCcb[rA][kg * 8];
      bf16x8 ac1 = *(const bf16x8*)&sCcb[rA][32 + kg * 8];
#pragma unroll
      for (int g = 0; g < 4; ++g) {
        acc[g] = mfma16(ac0, wga[g * 5 + 0], acc[g]);
        acc[g] = mfma16(ac1, wga[g * 5 + 1], acc[g]);
        acc[g] += *(const f32x4*)&sGPT[g * 128 + colH][kg * 4];
      }
#pragma unroll
      for (int i = 0; i < 4; ++i) {
        float ii = sigm(acc[0][i]);
        float ff = sigm(acc[1][i]);
        float g_ = tanh_fast(acc[2][i]);
        float oo = sigm(acc[3][i]);
        float c_ = ff * c_reg[i] + ii * g_;
        c_reg[i] = c_;
        h_reg[i] = oo * tanh_fast(c_);
      }
      if (t < NT - 1) {
        f32x4 ga4 = splat4(sB[192 + colH]);
        bf16x8 a0 = *(const bf16x8*)&sDb[p ^ 1][rA][kg * 8];
        bf16x8 a1 = *(const bf16x8*)&sDb[p ^ 1][rA][32 + kg * 8];
        ga4 = mfma16(a0, wga[20], ga4);
        ga4 = mfma16(a1, wga[21], ga4);
#pragma unroll
        for (int i = 0; i < 4; ++i) {
          float g = __expf(-fmaxf(ga4[i], 0.f));
          h_reg[i] *= g;
          sHb[p ^ 1][kg * 4 + i][colH] = f2bf(h_reg[i]);
        }
      } else {
#pragma unroll
        for (int i = 0; i < 4; ++i) out_h[(size_t)(b0 + kg * 4 + i) * 128 + colH] = h_reg[i];
      }
    }
    if (w < 4) {
      // est/imp coalesced stores
      size_t go = gb + (size_t)(t << 6);
      *(f32x4*)&out_est[go] = *(const f32x4*)&sCh[srow][sq * 4];
      *(f32x4*)&out_imp[go] = *(const f32x4*)&sCc[srow][sq * 4];
    } else if (w < 8) {
      if (t < NT - 1) {   // gamma_x(t+1)
        int f0 = sq * 4;
        u32x2 dp = *(const u32x2*)&sDb[p ^ 1][srow][f0];
        float g0 = __expf(-fmaxf(bf2f(dp[0] & 0xffffu) * sWdxB[f0]     + sWdxB[64 + f0],     0.f));
        float g1 = __expf(-fmaxf(bf2f(dp[0] >> 16)     * sWdxB[f0 + 1] + sWdxB[64 + f0 + 1], 0.f));
        float g2 = __expf(-fmaxf(bf2f(dp[1] & 0xffffu) * sWdxB[f0 + 2] + sWdxB[64 + f0 + 2], 0.f));
        float g3 = __expf(-fmaxf(bf2f(dp[1] >> 16)     * sWdxB[f0 + 3] + sWdxB[64 + f0 + 3], 0.f));
        u32x2 gp; gp[0] = pk2(g0, g1); gp[1] = pk2(g2, g3);
        *(u32x2*)&sGxb[srow][f0] = gp;
      }
    } else {
      // twins: issue t+2 loads + loss for step t
      int tq = (t + 2 <= NT - 1) ? t + 2 : NT - 1;
      size_t ga = gb + (size_t)(tq << 6);
      vx = *(const f32x4*)&values[ga];
      vm = *(const f32x4*)&masks[ga];
      vd = *(const f32x4*)&deltas[ga];
      f32x4 xv  = *(const f32x4*)&sX[p][srow][sq * 4];
      f32x4 chv = *(const f32x4*)&sCh[srow][sq * 4];
      u16x4 mv  = *(const u16x4*)&sMb[p][srow][sq * 4];
      u16x4 xhv = *(const u16x4*)&sXhb[srow][sq * 4];
      u16x4 zhv = *(const u16x4*)&sZhb[srow][sq * 4];
      float n1 = 0.f, n2 = 0.f, n3 = 0.f, den = 0.f;
#pragma unroll
      for (int j = 0; j < 4; ++j) {
        float m = bf2f(mv[j]);
        float x = xv[j];
        n1 += fabsf(bf2f(xhv[j]) - x) * m;
        n2 += fabsf(bf2f(zhv[j]) - x) * m;
        n3 += fabsf(chv[j] - x) * m;
        den += m;
      }
#pragma unroll
      for (int off = 32; off > 0; off >>= 1) {
        n1 += __shfl_down(n1, off);
        n2 += __shfl_down(n2, off);
        n3 += __shfl_down(n3, off);
        den += __shfl_down(den, off);
      }
      if (l == 0) {
        f32x4 lv; lv[0] = n1; lv[1] = n2; lv[2] = n3; lv[3] = den;
        *(f32x4*)&sLoss[w - 8][0] = lv;
      }
    }
    LGKM_BAR();   // bar C: sHb[p^1], sGxb, sLoss ready
  }

  // final loss_ws writeback for t = NT-1
  if (tid < 4) {
    float lsv = sLoss[0][tid] + sLoss[1][tid] + sLoss[2][tid] + sLoss[3][tid];
    loss_ws[((size_t)(NT - 1) * NBLK + wg) * 4 + tid] = lsv;
  }
}

__global__ void rits_loss_kernel(const float* __restrict__ ws, float* __restrict__ out_loss) {
  int tid = threadIdx.x;  // 64 threads; thread t handles step t
  float n1 = 0.f, n2 = 0.f, n3 = 0.f, den = 0.f;
  for (int g = 0; g < NBLK; ++g) {
    const float* p = &ws[((size_t)tid * NBLK + g) * 4];
    n1 += p[0]; n2 += p[1]; n3 += p[2]; den += p[3];
  }
  float lt = (n1 + n2 + n3) / (den + 1e-12f);
#pragma unroll
  for (int off = 32; off > 0; off >>= 1) lt += __shfl_down(lt, off);
  if (tid == 0) out_loss[0] = lt / 192.f;   // / (T * 3)
}

extern "C" void kernel_launch(void* const* d_in, const int* in_sizes, int n_in,
                              void* d_out, int out_size, void* d_ws, size_t ws_size,
                              hipStream_t stream) {
  const float* values = (const float*)d_in[0];
  const float* masks  = (const float*)d_in[1];
  const float* deltas = (const float*)d_in[2];
  const float* W_dh   = (const float*)d_in[3];
  const float* b_dh   = (const float*)d_in[4];
  const float* W_dx   = (const float*)d_in[5];
  const float* b_dx   = (const float*)d_in[6];
  const float* W_hist = (const float*)d_in[7];
  const float* b_hist = (const float*)d_in[8];
  const float* W_feat = (const float*)d_in[9];
  const float* b_feat = (const float*)d_in[10];
  const float* W_comb = (const float*)d_in[11];
  const float* b_comb = (const float*)d_in[12];
  const float* W_ih   = (const float*)d_in[13];
  const float* b_ih   = (const float*)d_in[14];
  const float* W_hh   = (const float*)d_in[15];
  const float* b_hh   = (const float*)d_in[16];

  float* out = (float*)d_out;
  float* out_imp = out;                       // [B,T,F]
  float* out_est = out + (size_t)BTF;         // [B,T,F]
  float* out_h   = out + (size_t)2 * BTF;     // [B,H]
  float* out_ls  = out + (size_t)2 * BTF + (size_t)NB * 128;  // scalar
  float* loss_ws = (float*)d_ws;              // [T][NBLK][4]

  rits_main_kernel<<<NBLK, 768, 0, stream>>>(
      values, masks, deltas, W_dh, b_dh, W_dx, b_dx, W_hist, b_hist,
      W_feat, b_feat, W_comb, b_comb, W_ih, b_ih, W_hh, b_hh,
      out_imp, out_est, out_h, loss_ws);
  rits_loss_kernel<<<1, 64, 0, stream>>>(loss_ws, out_ls);
}

// Round 13
// 256.972 us; speedup vs baseline: 2.4676x; 2.1767x over previous
//
#include <hip/hip_runtime.h>

typedef float f32x4 __attribute__((ext_vector_type(4)));
typedef unsigned int u32x2 __attribute__((ext_vector_type(2)));
typedef __bf16 bf16x2 __attribute__((ext_vector_type(2)));
typedef __bf16 bf16x8 __attribute__((ext_vector_type(8)));

static_assert(sizeof(bf16x8) == 16, "bf16x8 must be 16B");

#define NB 4096
#define NT 64
#define NBLK 256
#define BTF (NB * NT * 64)   // 16777216

// Barrier draining ONLY lgkmcnt (LDS); global loads/stores stay in flight.
#define LGKM_BAR() do { \
    asm volatile("s_waitcnt lgkmcnt(0)" ::: "memory"); \
    __builtin_amdgcn_s_barrier(); \
  } while (0)

__device__ __forceinline__ unsigned short f2bf(float x) {
  return __builtin_bit_cast(unsigned short, (__bf16)x);
}
__device__ __forceinline__ unsigned int pk2(float lo, float hi) {
  bf16x2 t; t[0] = (__bf16)lo; t[1] = (__bf16)hi;
  return __builtin_bit_cast(unsigned int, t);
}
__device__ __forceinline__ float bf2f(unsigned int us) {   // low 16 bits -> f32
  return __builtin_bit_cast(float, us << 16);
}

__device__ __forceinline__ f32x4 mfma16(bf16x8 a, bf16x8 b, f32x4 c) {
  return __builtin_amdgcn_mfma_f32_16x16x32_bf16(a, b, c, 0, 0, 0);
}

__device__ __forceinline__ bf16x8 cvt8(f32x4 a, f32x4 b) {
  bf16x8 r;
#pragma unroll
  for (int j = 0; j < 4; ++j) { r[j] = (__bf16)a[j]; r[4 + j] = (__bf16)b[j]; }
  return r;
}

__device__ __forceinline__ bf16x8 loadW8(const float* __restrict__ row, int k0) {
  f32x4 a = *(const f32x4*)(row + k0);
  f32x4 b = *(const f32x4*)(row + k0 + 4);
  return cvt8(a, b);
}

__device__ __forceinline__ bf16x8 loadW8zd(const float* __restrict__ row, int k0, int col) {
  f32x4 a = *(const f32x4*)(row + k0);
  f32x4 b = *(const f32x4*)(row + k0 + 4);
  bf16x8 r;
#pragma unroll
  for (int j = 0; j < 4; ++j) {
    r[j]     = (k0 + j     == col) ? (__bf16)0.f : (__bf16)a[j];
    r[4 + j] = (k0 + 4 + j == col) ? (__bf16)0.f : (__bf16)b[j];
  }
  return r;
}

__device__ __forceinline__ float sigm(float x) { return 1.f / (1.f + __expf(-x)); }
__device__ __forceinline__ float tanh_fast(float x) { return 1.f - 2.f / (__expf(2.f * x) + 1.f); }

__global__ __launch_bounds__(512, 2) void rits_main_kernel(
    const float* __restrict__ values, const float* __restrict__ masks,
    const float* __restrict__ deltas,
    const float* __restrict__ W_dh, const float* __restrict__ b_dh,
    const float* __restrict__ W_dx, const float* __restrict__ b_dx,
    const float* __restrict__ W_hist, const float* __restrict__ b_hist,
    const float* __restrict__ W_feat, const float* __restrict__ b_feat,
    const float* __restrict__ W_comb, const float* __restrict__ b_comb,
    const float* __restrict__ W_ih, const float* __restrict__ b_ih,
    const float* __restrict__ W_hh, const float* __restrict__ b_hh,
    float* __restrict__ out_imp, float* __restrict__ out_est,
    float* __restrict__ out_h, float* __restrict__ loss_ws) {
  const int tid = threadIdx.x;
  const int w = tid >> 6;          // wave 0..7
  const int l = tid & 63;          // lane
  const int rA = l & 15;           // MFMA A-row / C-col index
  const int kg = l >> 4;           // k-group 0..3
  const int wg = blockIdx.x;
  const int b0 = wg * 16;
  const int colh = w * 16 + rA;          // 0..127
  const int colw = (w & 3) * 16 + rA;    // 0..63
  const int s = tid & 255;               // staging index
  const int sr = s >> 4, sq = s & 15;    // 16 rows x 16 quads

  __shared__ float sX[2][16][68];                            // x f32 (exact)
  __shared__ unsigned short sMb[2][16][72], sDb[2][16][72];  // m, d bf16
  __shared__ unsigned short sHb[2][16][136];                 // decayed h~
  __shared__ unsigned short sXcb[16][72], sCcb[16][72];
  __shared__ unsigned short sGxb[16][72];                    // gamma_x bf16
  __shared__ float sAlT[64][20];                             // alpha, TRANSPOSED [col][row]
  __shared__ float sCh[16][68], sCc[16][68];
  __shared__ float sWdxB[128];                               // diag(W_dx) | b_dx
  __shared__ float sLoss[4][4];

  // ---------------- one-time init ----------------
  if (tid < 64)       sWdxB[tid] = W_dx[tid * 65];
  else if (tid < 128) sWdxB[tid] = b_dx[tid - 64];
#pragma unroll
  for (int i = 0; i < 4; ++i) sHb[0][kg * 4 + i][colh] = 0;   // h~(0) = 0

  // ---------------- weights -> registers ----------------
  bf16x8 wgf[4][8];
#pragma unroll
  for (int g = 0; g < 4; ++g) {
    int col = g * 128 + colh;
#pragma unroll
    for (int kk = 0; kk < 4; ++kk) wgf[g][kk] = loadW8(W_ih + (size_t)col * 128, kk * 32 + kg * 8);
#pragma unroll
    for (int kk = 0; kk < 4; ++kk) wgf[g][4 + kk] = loadW8(W_hh + (size_t)col * 128, kk * 32 + kg * 8);
  }
  bf16x8 wdhf[2];
#pragma unroll
  for (int kk = 0; kk < 2; ++kk) wdhf[kk] = loadW8(W_dh + (size_t)colh * 64, kk * 32 + kg * 8);

  bf16x8 wsm[4], wfeat[2];
  if (w < 4) {
#pragma unroll
    for (int kk = 0; kk < 4; ++kk) wsm[kk] = loadW8(W_hist + (size_t)colw * 128, kk * 32 + kg * 8);
#pragma unroll
    for (int kk = 0; kk < 2; ++kk) wfeat[kk] = loadW8zd(W_feat + (size_t)colw * 64, kk * 32 + kg * 8, colw);
  } else {
#pragma unroll
    for (int kk = 0; kk < 4; ++kk) wsm[kk] = loadW8(W_comb + (size_t)colw * 128, kk * 32 + kg * 8);
#pragma unroll
    for (int kk = 0; kk < 2; ++kk) { bf16x8 z = {}; wfeat[kk] = z; }
  }

  const float bdh = b_dh[colh];
  const float bhist = (w < 4) ? b_hist[colw] : 0.f;
  const float bfeat = (w < 4) ? b_feat[colw] : 0.f;
  const float bcomb = (w >= 4) ? b_comb[colw] : 0.f;
  float bg[4];
#pragma unroll
  for (int g = 0; g < 4; ++g) bg[g] = b_ih[g * 128 + colh] + b_hh[g * 128 + colh];

  f32x4 h_reg = {0.f, 0.f, 0.f, 0.f};
  f32x4 c_reg = {0.f, 0.f, 0.f, 0.f};

  // hoisted global bases
  const size_t gbase = (size_t)(b0 + sr) * 4096 + sq * 4;     // staging (w>=4)
  const int orow = (tid & 255) >> 4, oq = tid & 15;
  float* pout = ((tid < 256) ? out_est : out_imp) + (size_t)(b0 + orow) * 4096 + oq * 4;
  const float* sOut0 = (tid < 256) ? &sCh[orow][oq * 4] : &sCc[orow][oq * 4];

  // ---------------- prologue: stage t=0 into buf 0 ----------------
  if (w >= 4) {
    f32x4 vx0 = *(const f32x4*)&values[gbase];
    f32x4 vm0 = *(const f32x4*)&masks[gbase];
    f32x4 vd0 = *(const f32x4*)&deltas[gbase];
    *(f32x4*)&sX[0][sr][sq * 4] = vx0;
    u32x2 pm, pd;
    pm[0] = pk2(vm0[0], vm0[1]); pm[1] = pk2(vm0[2], vm0[3]);
    pd[0] = pk2(vd0[0], vd0[1]); pd[1] = pk2(vd0[2], vd0[3]);
    *(u32x2*)&sMb[0][sr][sq * 4] = pm;
    *(u32x2*)&sDb[0][sr][sq * 4] = pd;
  }
  LGKM_BAR();

  // gamma_x(0) from sDb[0] + issue t=1 loads
  f32x4 vx, vm, vd;
  if (w >= 4) {
    vx = *(const f32x4*)&values[gbase + 64];
    vm = *(const f32x4*)&masks[gbase + 64];
    vd = *(const f32x4*)&deltas[gbase + 64];
  }
  {
    int e = tid * 2, rr = e >> 6, f0 = e & 63;
    unsigned int dp = *(const unsigned int*)&sDb[0][rr][f0];
    float g0 = __expf(-fmaxf(bf2f(dp & 0xffffu) * sWdxB[f0]     + sWdxB[64 + f0],     0.f));
    float g1 = __expf(-fmaxf(bf2f(dp >> 16)     * sWdxB[f0 + 1] + sWdxB[64 + f0 + 1], 0.f));
    *(unsigned int*)&sGxb[rr][f0] = pk2(g0, g1);
  }
  LGKM_BAR();

  // ---------------- time loop: 3 lgkm-only barriers per step ----------------
  for (int t = 0; t < NT; ++t) {
    const int p = t & 1;

    // ---- P2: loss_ws(t-1) writeback; w<4: x_h GEMM + x_c; w>=4: alpha GEMM ----
    if (t > 0 && tid < 4) {
      float ls = sLoss[0][tid] + sLoss[1][tid] + sLoss[2][tid] + sLoss[3][tid];
      loss_ws[((size_t)(t - 1) * NBLK + wg) * 4 + tid] = ls;
    }
    float xh[4], xr[4], mr[4];
    float n1 = 0.f, n2 = 0.f, n3 = 0.f, den = 0.f;
    if (w < 4) {
      f32x4 axh = {0.f, 0.f, 0.f, 0.f};
#pragma unroll
      for (int kk = 0; kk < 4; ++kk) {
        bf16x8 a = *(const bf16x8*)&sHb[p][rA][kk * 32 + kg * 8];
        axh = mfma16(a, wsm[kk], axh);
      }
#pragma unroll
      for (int i = 0; i < 4; ++i) {
        int row = kg * 4 + i;
        xr[i] = sX[p][row][colw];
        mr[i] = bf2f(sMb[p][row][colw]);   // m is exactly 0/1 in bf16
        xh[i] = axh[i] + bhist;
        float xc = mr[i] * xr[i] + (1.f - mr[i]) * xh[i];
        sXcb[row][colw] = f2bf(xc);
      }
    } else {
      f32x4 aal = {0.f, 0.f, 0.f, 0.f};
      bf16x8 a0 = *(const bf16x8*)&sGxb[rA][kg * 8];
      bf16x8 a1 = *(const bf16x8*)&sGxb[rA][32 + kg * 8];
      aal = mfma16(a0, wsm[0], aal);
      aal = mfma16(a1, wsm[1], aal);
      bf16x8 a2 = *(const bf16x8*)&sMb[p][rA][kg * 8];
      bf16x8 a3 = *(const bf16x8*)&sMb[p][rA][32 + kg * 8];
      aal = mfma16(a2, wsm[2], aal);
      aal = mfma16(a3, wsm[3], aal);
      f32x4 alv;
#pragma unroll
      for (int i = 0; i < 4; ++i) alv[i] = sigm(aal[i] + bcomb);
      *(f32x4*)&sAlT[colw][kg * 4] = alv;   // transposed write, one b128
#pragma unroll
      for (int i = 0; i < 4; ++i) { xh[i] = 0.f; xr[i] = 0.f; mr[i] = 0.f; }
    }
    LGKM_BAR();   // bar A: sXcb, sAlT ready

    // ---- P3: w<4: z_h + c_h/c_c + loss partials; w>=4: staging writes;
    //          ALL: 24 gate MFMAs on bar-A-stable m/h~ fragments ----
    f32x4 acc[4];
#pragma unroll
    for (int g = 0; g < 4; ++g) { f32x4 z = {0.f, 0.f, 0.f, 0.f}; acc[g] = z; }
    if (w < 4) {
      f32x4 azh = {0.f, 0.f, 0.f, 0.f};
      bf16x8 ax0 = *(const bf16x8*)&sXcb[rA][kg * 8];
      bf16x8 ax1 = *(const bf16x8*)&sXcb[rA][32 + kg * 8];
      azh = mfma16(ax0, wfeat[0], azh);
      azh = mfma16(ax1, wfeat[1], azh);
      f32x4 alv = *(const f32x4*)&sAlT[colw][kg * 4];   // one b128
#pragma unroll
      for (int i = 0; i < 4; ++i) {
        int row = kg * 4 + i;
        float zh = azh[i] + bfeat;
        float al = alv[i];
        float ch = al * zh + (1.f - al) * xh[i];
        float cc = mr[i] * xr[i] + (1.f - mr[i]) * ch;
        sCh[row][colw] = ch;
        sCc[row][colw] = cc;
        sCcb[row][colw] = f2bf(cc);
        n1 += fabsf(xh[i] - xr[i]) * mr[i];
        n2 += fabsf(zh - xr[i]) * mr[i];
        n3 += fabsf(ch - xr[i]) * mr[i];
        den += mr[i];
      }
    } else {
      // vmcnt wait for vx/vm/vd lands here (issued ~3 phases ago)
      *(f32x4*)&sX[p ^ 1][sr][sq * 4] = vx;
      u32x2 pm, pd;
      pm[0] = pk2(vm[0], vm[1]); pm[1] = pk2(vm[2], vm[3]);
      pd[0] = pk2(vd[0], vd[1]); pd[1] = pk2(vd[2], vd[3]);
      *(u32x2*)&sMb[p ^ 1][sr][sq * 4] = pm;
      *(u32x2*)&sDb[p ^ 1][sr][sq * 4] = pd;
    }
    // 24 gate MFMAs on stable fragments (operands read + consumed in-phase)
    {
      bf16x8 fm0 = *(const bf16x8*)&sMb[p][rA][kg * 8];
      bf16x8 fm1 = *(const bf16x8*)&sMb[p][rA][32 + kg * 8];
      bf16x8 fh0 = *(const bf16x8*)&sHb[p][rA][kg * 8];
      bf16x8 fh1 = *(const bf16x8*)&sHb[p][rA][32 + kg * 8];
      bf16x8 fh2 = *(const bf16x8*)&sHb[p][rA][64 + kg * 8];
      bf16x8 fh3 = *(const bf16x8*)&sHb[p][rA][96 + kg * 8];
#pragma unroll
      for (int g = 0; g < 4; ++g) acc[g] = mfma16(fm0, wgf[g][2], acc[g]);
#pragma unroll
      for (int g = 0; g < 4; ++g) acc[g] = mfma16(fm1, wgf[g][3], acc[g]);
#pragma unroll
      for (int g = 0; g < 4; ++g) acc[g] = mfma16(fh0, wgf[g][4], acc[g]);
#pragma unroll
      for (int g = 0; g < 4; ++g) acc[g] = mfma16(fh1, wgf[g][5], acc[g]);
#pragma unroll
      for (int g = 0; g < 4; ++g) acc[g] = mfma16(fh2, wgf[g][6], acc[g]);
#pragma unroll
      for (int g = 0; g < 4; ++g) acc[g] = mfma16(fh3, wgf[g][7], acc[g]);
    }
    LGKM_BAR();   // bar B: sCcb/sCh/sCc + staged t+1 ready

    // ---- E: c_c MFMAs + loss shuffle (DS pipe, overlapped) + LSTM + gamma(t+1) ----
    if (w >= 4) {   // issue t+2 loads
      int tq = (t + 2 <= NT - 1) ? t + 2 : NT - 1;
      size_t ga = gbase + (size_t)(tq << 6);
      vx = *(const f32x4*)&values[ga];
      vm = *(const f32x4*)&masks[ga];
      vd = *(const f32x4*)&deltas[ga];
    }
    // est/imp coalesced stores (running pointer)
    *(f32x4*)pout = *(const f32x4*)sOut0;
    pout += 64;
    {
      bf16x8 ac0 = *(const bf16x8*)&sCcb[rA][kg * 8];
      bf16x8 ac1 = *(const bf16x8*)&sCcb[rA][32 + kg * 8];
#pragma unroll
      for (int g = 0; g < 4; ++g) acc[g] = mfma16(ac0, wgf[g][0], acc[g]);
#pragma unroll
      for (int g = 0; g < 4; ++g) acc[g] = mfma16(ac1, wgf[g][1], acc[g]);
    }
    // loss shuffle tree: DS-pipe ops overlap the MFMA/VALU pipes
    if (w < 4) {
#pragma unroll
      for (int off = 32; off > 0; off >>= 1) {
        n1 += __shfl_down(n1, off);
        n2 += __shfl_down(n2, off);
        n3 += __shfl_down(n3, off);
        den += __shfl_down(den, off);
      }
      if (l == 0) {
        f32x4 lv; lv[0] = n1; lv[1] = n2; lv[2] = n3; lv[3] = den;
        *(f32x4*)&sLoss[w][0] = lv;
      }
    }
    // LSTM nonlinearity
#pragma unroll
    for (int i = 0; i < 4; ++i) {
      float ii = sigm(acc[0][i] + bg[0]);
      float ff = sigm(acc[1][i] + bg[1]);
      float g_ = tanh_fast(acc[2][i] + bg[2]);
      float oo = sigm(acc[3][i] + bg[3]);
      float c_ = ff * c_reg[i] + ii * g_;
      c_reg[i] = c_;
      h_reg[i] = oo * tanh_fast(c_);
    }
    if (t < NT - 1) {
      // gamma_h(t+1) from staged d(t+1); decay h into sHb[p^1]
      bf16x8 a0 = *(const bf16x8*)&sDb[p ^ 1][rA][kg * 8];
      bf16x8 a1 = *(const bf16x8*)&sDb[p ^ 1][rA][32 + kg * 8];
      f32x4 ga4 = {0.f, 0.f, 0.f, 0.f};
      ga4 = mfma16(a0, wdhf[0], ga4);
      ga4 = mfma16(a1, wdhf[1], ga4);
#pragma unroll
      for (int i = 0; i < 4; ++i) {
        float g = __expf(-fmaxf(ga4[i] + bdh, 0.f));
        h_reg[i] *= g;
        sHb[p ^ 1][kg * 4 + i][colh] = f2bf(h_reg[i]);
      }
      // gamma_x(t+1) dedup from sDb[p^1]
      int e = tid * 2, rr = e >> 6, f0 = e & 63;
      unsigned int dp = *(const unsigned int*)&sDb[p ^ 1][rr][f0];
      float g0 = __expf(-fmaxf(bf2f(dp & 0xffffu) * sWdxB[f0]     + sWdxB[64 + f0],     0.f));
      float g1 = __expf(-fmaxf(bf2f(dp >> 16)     * sWdxB[f0 + 1] + sWdxB[64 + f0 + 1], 0.f));
      *(unsigned int*)&sGxb[rr][f0] = pk2(g0, g1);
    } else {
#pragma unroll
      for (int i = 0; i < 4; ++i) out_h[(size_t)(b0 + kg * 4 + i) * 128 + colh] = h_reg[i];
    }
    LGKM_BAR();   // bar C: sHb[p^1], sGxb, sLoss ready; step-t LDS reads complete
  }

  // final loss_ws writeback for t = NT-1
  if (tid < 4) {
    float ls = sLoss[0][tid] + sLoss[1][tid] + sLoss[2][tid] + sLoss[3][tid];
    loss_ws[((size_t)(NT - 1) * NBLK + wg) * 4 + tid] = ls;
  }
}

__global__ void rits_loss_kernel(const float* __restrict__ ws, float* __restrict__ out_loss) {
  int tid = threadIdx.x;  // 64 threads; thread t handles step t
  float n1 = 0.f, n2 = 0.f, n3 = 0.f, den = 0.f;
  for (int g = 0; g < NBLK; ++g) {
    const float* p = &ws[((size_t)tid * NBLK + g) * 4];
    n1 += p[0]; n2 += p[1]; n3 += p[2]; den += p[3];
  }
  float lt = (n1 + n2 + n3) / (den + 1e-12f);
#pragma unroll
  for (int off = 32; off > 0; off >>= 1) lt += __shfl_down(lt, off);
  if (tid == 0) out_loss[0] = lt / 192.f;   // / (T * 3)
}

extern "C" void kernel_launch(void* const* d_in, const int* in_sizes, int n_in,
                              void* d_out, int out_size, void* d_ws, size_t ws_size,
                              hipStream_t stream) {
  const float* values = (const float*)d_in[0];
  const float* masks  = (const float*)d_in[1];
  const float* deltas = (const float*)d_in[2];
  const float* W_dh   = (const float*)d_in[3];
  const float* b_dh   = (const float*)d_in[4];
  const float* W_dx   = (const float*)d_in[5];
  const float* b_dx   = (const float*)d_in[6];
  const float* W_hist = (const float*)d_in[7];
  const float* b_hist = (const float*)d_in[8];
  const float* W_feat = (const float*)d_in[9];
  const float* b_feat = (const float*)d_in[10];
  const float* W_comb = (const float*)d_in[11];
  const float* b_comb = (const float*)d_in[12];
  const float* W_ih   = (const float*)d_in[13];
  const float* b_ih   = (const float*)d_in[14];
  const float* W_hh   = (const float*)d_in[15];
  const float* b_hh   = (const float*)d_in[16];

  float* out = (float*)d_out;
  float* out_imp = out;                       // [B,T,F]
  float* out_est = out + (size_t)BTF;         // [B,T,F]
  float* out_h   = out + (size_t)2 * BTF;     // [B,H]
  float* out_ls  = out + (size_t)2 * BTF + (size_t)NB * 128;  // scalar
  float* loss_ws = (float*)d_ws;              // [T][NBLK][4]

  rits_main_kernel<<<NBLK, 512, 0, stream>>>(
      values, masks, deltas, W_dh, b_dh, W_dx, b_dx, W_hist, b_hist,
      W_feat, b_feat, W_comb, b_comb, W_ih, b_ih, W_hh, b_hh,
      out_imp, out_est, out_h, loss_ws);
  rits_loss_kernel<<<1, 64, 0, stream>>>(loss_ws, out_ls);
}

// Round 14
// 206.920 us; speedup vs baseline: 3.0645x; 1.2419x over previous
//
#include <hip/hip_runtime.h>

typedef float f32x4 __attribute__((ext_vector_type(4)));
typedef unsigned int u32x2 __attribute__((ext_vector_type(2)));
typedef __bf16 bf16x2 __attribute__((ext_vector_type(2)));
typedef __bf16 bf16x8 __attribute__((ext_vector_type(8)));

static_assert(sizeof(bf16x8) == 16, "bf16x8 must be 16B");

#define NB 4096
#define NT 64
#define NBLK 256
#define BTF (NB * NT * 64)   // 16777216

// Barrier draining ONLY lgkmcnt (LDS); global loads/stores stay in flight.
#define LGKM_BAR() do { \
    asm volatile("s_waitcnt lgkmcnt(0)" ::: "memory"); \
    __builtin_amdgcn_s_barrier(); \
  } while (0)

__device__ __forceinline__ unsigned short f2bf(float x) {
  return __builtin_bit_cast(unsigned short, (__bf16)x);
}
__device__ __forceinline__ unsigned int pk2(float lo, float hi) {
  bf16x2 t; t[0] = (__bf16)lo; t[1] = (__bf16)hi;
  return __builtin_bit_cast(unsigned int, t);
}
__device__ __forceinline__ float bf2f(unsigned int us) {   // low 16 bits -> f32
  return __builtin_bit_cast(float, us << 16);
}

__device__ __forceinline__ f32x4 mfma16(bf16x8 a, bf16x8 b, f32x4 c) {
  return __builtin_amdgcn_mfma_f32_16x16x32_bf16(a, b, c, 0, 0, 0);
}

__device__ __forceinline__ bf16x8 cvt8(f32x4 a, f32x4 b) {
  bf16x8 r;
#pragma unroll
  for (int j = 0; j < 4; ++j) { r[j] = (__bf16)a[j]; r[4 + j] = (__bf16)b[j]; }
  return r;
}

__device__ __forceinline__ bf16x8 loadW8(const float* __restrict__ row, int k0) {
  f32x4 a = *(const f32x4*)(row + k0);
  f32x4 b = *(const f32x4*)(row + k0 + 4);
  return cvt8(a, b);
}

__device__ __forceinline__ bf16x8 loadW8zd(const float* __restrict__ row, int k0, int col) {
  f32x4 a = *(const f32x4*)(row + k0);
  f32x4 b = *(const f32x4*)(row + k0 + 4);
  bf16x8 r;
#pragma unroll
  for (int j = 0; j < 4; ++j) {
    r[j]     = (k0 + j     == col) ? (__bf16)0.f : (__bf16)a[j];
    r[4 + j] = (k0 + 4 + j == col) ? (__bf16)0.f : (__bf16)b[j];
  }
  return r;
}

// Hardware-rcp nonlinearities: v_rcp_f32 (~1 ulp) replaces the ~10-op IEEE
// division sequence. Error is far below the bf16 noise floor downstream.
__device__ __forceinline__ float sigm(float x) {
  return __builtin_amdgcn_rcpf(1.f + __expf(-x));
}
__device__ __forceinline__ float tanh_fast(float x) {
  return 1.f - 2.f * __builtin_amdgcn_rcpf(__expf(2.f * x) + 1.f);
}

__global__ __launch_bounds__(512, 2) void rits_main_kernel(
    const float* __restrict__ values, const float* __restrict__ masks,
    const float* __restrict__ deltas,
    const float* __restrict__ W_dh, const float* __restrict__ b_dh,
    const float* __restrict__ W_dx, const float* __restrict__ b_dx,
    const float* __restrict__ W_hist, const float* __restrict__ b_hist,
    const float* __restrict__ W_feat, const float* __restrict__ b_feat,
    const float* __restrict__ W_comb, const float* __restrict__ b_comb,
    const float* __restrict__ W_ih, const float* __restrict__ b_ih,
    const float* __restrict__ W_hh, const float* __restrict__ b_hh,
    float* __restrict__ out_imp, float* __restrict__ out_est,
    float* __restrict__ out_h, float* __restrict__ loss_ws) {
  const int tid = threadIdx.x;
  const int w = tid >> 6;          // wave 0..7
  const int l = tid & 63;          // lane
  const int rA = l & 15;           // MFMA A-row / C-col index
  const int kg = l >> 4;           // k-group 0..3
  const int wg = blockIdx.x;
  const int b0 = wg * 16;
  const int colh = w * 16 + rA;          // 0..127
  const int colw = (w & 3) * 16 + rA;    // 0..63
  const int s = tid & 255;               // staging index
  const int sr = s >> 4, sq = s & 15;    // 16 rows x 16 quads

  __shared__ float sX[2][16][68];                            // x f32 (exact)
  __shared__ unsigned short sMb[2][16][72], sDb[2][16][72];  // m, d bf16
  __shared__ unsigned short sHb[2][16][136];                 // decayed h~
  __shared__ unsigned short sXcb[16][72], sCcb[16][72];
  __shared__ unsigned short sGxb[16][72];                    // gamma_x bf16
  __shared__ float sAlT[64][20];                             // alpha, TRANSPOSED [col][row]
  __shared__ float sCh[16][68], sCc[16][68];
  __shared__ float sWdxB[128];                               // diag(W_dx) | b_dx
  __shared__ float sLoss[4][4];

  // ---------------- one-time init ----------------
  if (tid < 64)       sWdxB[tid] = W_dx[tid * 65];
  else if (tid < 128) sWdxB[tid] = b_dx[tid - 64];
#pragma unroll
  for (int i = 0; i < 4; ++i) sHb[0][kg * 4 + i][colh] = 0;   // h~(0) = 0

  // ---------------- weights -> registers ----------------
  bf16x8 wgf[4][8];
#pragma unroll
  for (int g = 0; g < 4; ++g) {
    int col = g * 128 + colh;
#pragma unroll
    for (int kk = 0; kk < 4; ++kk) wgf[g][kk] = loadW8(W_ih + (size_t)col * 128, kk * 32 + kg * 8);
#pragma unroll
    for (int kk = 0; kk < 4; ++kk) wgf[g][4 + kk] = loadW8(W_hh + (size_t)col * 128, kk * 32 + kg * 8);
  }
  bf16x8 wdhf[2];
#pragma unroll
  for (int kk = 0; kk < 2; ++kk) wdhf[kk] = loadW8(W_dh + (size_t)colh * 64, kk * 32 + kg * 8);

  bf16x8 wsm[4], wfeat[2];
  if (w < 4) {
#pragma unroll
    for (int kk = 0; kk < 4; ++kk) wsm[kk] = loadW8(W_hist + (size_t)colw * 128, kk * 32 + kg * 8);
#pragma unroll
    for (int kk = 0; kk < 2; ++kk) wfeat[kk] = loadW8zd(W_feat + (size_t)colw * 64, kk * 32 + kg * 8, colw);
  } else {
#pragma unroll
    for (int kk = 0; kk < 4; ++kk) wsm[kk] = loadW8(W_comb + (size_t)colw * 128, kk * 32 + kg * 8);
#pragma unroll
    for (int kk = 0; kk < 2; ++kk) { bf16x8 z = {}; wfeat[kk] = z; }
  }

  const float bdh = b_dh[colh];
  const float bhist = (w < 4) ? b_hist[colw] : 0.f;
  const float bfeat = (w < 4) ? b_feat[colw] : 0.f;
  const float bcomb = (w >= 4) ? b_comb[colw] : 0.f;
  float bg[4];
#pragma unroll
  for (int g = 0; g < 4; ++g) bg[g] = b_ih[g * 128 + colh] + b_hh[g * 128 + colh];

  f32x4 h_reg = {0.f, 0.f, 0.f, 0.f};
  f32x4 c_reg = {0.f, 0.f, 0.f, 0.f};

  // hoisted global bases
  const size_t gbase = (size_t)(b0 + sr) * 4096 + sq * 4;     // staging (w>=4)
  const int orow = (tid & 255) >> 4, oq = tid & 15;
  float* pout = ((tid < 256) ? out_est : out_imp) + (size_t)(b0 + orow) * 4096 + oq * 4;
  const float* sOut0 = (tid < 256) ? &sCh[orow][oq * 4] : &sCc[orow][oq * 4];

  // ---------------- prologue: stage t=0 into buf 0 ----------------
  if (w >= 4) {
    f32x4 vx0 = *(const f32x4*)&values[gbase];
    f32x4 vm0 = *(const f32x4*)&masks[gbase];
    f32x4 vd0 = *(const f32x4*)&deltas[gbase];
    *(f32x4*)&sX[0][sr][sq * 4] = vx0;
    u32x2 pm, pd;
    pm[0] = pk2(vm0[0], vm0[1]); pm[1] = pk2(vm0[2], vm0[3]);
    pd[0] = pk2(vd0[0], vd0[1]); pd[1] = pk2(vd0[2], vd0[3]);
    *(u32x2*)&sMb[0][sr][sq * 4] = pm;
    *(u32x2*)&sDb[0][sr][sq * 4] = pd;
  }
  LGKM_BAR();

  // gamma_x(0) from sDb[0] + issue t=1 loads
  f32x4 vx, vm, vd;
  if (w >= 4) {
    vx = *(const f32x4*)&values[gbase + 64];
    vm = *(const f32x4*)&masks[gbase + 64];
    vd = *(const f32x4*)&deltas[gbase + 64];
  }
  {
    int e = tid * 2, rr = e >> 6, f0 = e & 63;
    unsigned int dp = *(const unsigned int*)&sDb[0][rr][f0];
    float g0 = __expf(-fmaxf(bf2f(dp & 0xffffu) * sWdxB[f0]     + sWdxB[64 + f0],     0.f));
    float g1 = __expf(-fmaxf(bf2f(dp >> 16)     * sWdxB[f0 + 1] + sWdxB[64 + f0 + 1], 0.f));
    *(unsigned int*)&sGxb[rr][f0] = pk2(g0, g1);
  }
  LGKM_BAR();

  // ---------------- time loop: 3 lgkm-only barriers per step ----------------
  for (int t = 0; t < NT; ++t) {
    const int p = t & 1;

    // ---- P2: loss_ws(t-1) writeback; w<4: x_h GEMM + x_c; w>=4: alpha GEMM ----
    if (t > 0 && tid < 4) {
      float ls = sLoss[0][tid] + sLoss[1][tid] + sLoss[2][tid] + sLoss[3][tid];
      loss_ws[((size_t)(t - 1) * NBLK + wg) * 4 + tid] = ls;
    }
    float xh[4], xr[4], mr[4];
    float n1 = 0.f, n2 = 0.f, n3 = 0.f, den = 0.f;
    if (w < 4) {
      f32x4 axh = {0.f, 0.f, 0.f, 0.f};
#pragma unroll
      for (int kk = 0; kk < 4; ++kk) {
        bf16x8 a = *(const bf16x8*)&sHb[p][rA][kk * 32 + kg * 8];
        axh = mfma16(a, wsm[kk], axh);
      }
#pragma unroll
      for (int i = 0; i < 4; ++i) {
        int row = kg * 4 + i;
        xr[i] = sX[p][row][colw];
        mr[i] = bf2f(sMb[p][row][colw]);   // m is exactly 0/1 in bf16
        xh[i] = axh[i] + bhist;
        float xc = mr[i] * xr[i] + (1.f - mr[i]) * xh[i];
        sXcb[row][colw] = f2bf(xc);
      }
    } else {
      f32x4 aal = {0.f, 0.f, 0.f, 0.f};
      bf16x8 a0 = *(const bf16x8*)&sGxb[rA][kg * 8];
      bf16x8 a1 = *(const bf16x8*)&sGxb[rA][32 + kg * 8];
      aal = mfma16(a0, wsm[0], aal);
      aal = mfma16(a1, wsm[1], aal);
      bf16x8 a2 = *(const bf16x8*)&sMb[p][rA][kg * 8];
      bf16x8 a3 = *(const bf16x8*)&sMb[p][rA][32 + kg * 8];
      aal = mfma16(a2, wsm[2], aal);
      aal = mfma16(a3, wsm[3], aal);
      f32x4 alv;
#pragma unroll
      for (int i = 0; i < 4; ++i) alv[i] = sigm(aal[i] + bcomb);
      *(f32x4*)&sAlT[colw][kg * 4] = alv;   // transposed write, one b128
#pragma unroll
      for (int i = 0; i < 4; ++i) { xh[i] = 0.f; xr[i] = 0.f; mr[i] = 0.f; }
    }
    LGKM_BAR();   // bar A: sXcb, sAlT ready

    // ---- P3: w<4: z_h + c_h/c_c + loss partials; w>=4: staging writes;
    //          ALL: 24 gate MFMAs on bar-A-stable m/h~ fragments ----
    f32x4 acc[4];
#pragma unroll
    for (int g = 0; g < 4; ++g) { f32x4 z = {0.f, 0.f, 0.f, 0.f}; acc[g] = z; }
    if (w < 4) {
      f32x4 azh = {0.f, 0.f, 0.f, 0.f};
      bf16x8 ax0 = *(const bf16x8*)&sXcb[rA][kg * 8];
      bf16x8 ax1 = *(const bf16x8*)&sXcb[rA][32 + kg * 8];
      azh = mfma16(ax0, wfeat[0], azh);
      azh = mfma16(ax1, wfeat[1], azh);
      f32x4 alv = *(const f32x4*)&sAlT[colw][kg * 4];   // one b128
#pragma unroll
      for (int i = 0; i < 4; ++i) {
        int row = kg * 4 + i;
        float zh = azh[i] + bfeat;
        float al = alv[i];
        float ch = al * zh + (1.f - al) * xh[i];
        float cc = mr[i] * xr[i] + (1.f - mr[i]) * ch;
        sCh[row][colw] = ch;
        sCc[row][colw] = cc;
        sCcb[row][colw] = f2bf(cc);
        n1 += fabsf(xh[i] - xr[i]) * mr[i];
        n2 += fabsf(zh - xr[i]) * mr[i];
        n3 += fabsf(ch - xr[i]) * mr[i];
        den += mr[i];
      }
    } else {
      // vmcnt wait for vx/vm/vd lands here (issued ~3 phases ago)
      *(f32x4*)&sX[p ^ 1][sr][sq * 4] = vx;
      u32x2 pm, pd;
      pm[0] = pk2(vm[0], vm[1]); pm[1] = pk2(vm[2], vm[3]);
      pd[0] = pk2(vd[0], vd[1]); pd[1] = pk2(vd[2], vd[3]);
      *(u32x2*)&sMb[p ^ 1][sr][sq * 4] = pm;
      *(u32x2*)&sDb[p ^ 1][sr][sq * 4] = pd;
    }
    // 24 gate MFMAs on stable fragments (operands read + consumed in-phase)
    {
      bf16x8 fm0 = *(const bf16x8*)&sMb[p][rA][kg * 8];
      bf16x8 fm1 = *(const bf16x8*)&sMb[p][rA][32 + kg * 8];
      bf16x8 fh0 = *(const bf16x8*)&sHb[p][rA][kg * 8];
      bf16x8 fh1 = *(const bf16x8*)&sHb[p][rA][32 + kg * 8];
      bf16x8 fh2 = *(const bf16x8*)&sHb[p][rA][64 + kg * 8];
      bf16x8 fh3 = *(const bf16x8*)&sHb[p][rA][96 + kg * 8];
#pragma unroll
      for (int g = 0; g < 4; ++g) acc[g] = mfma16(fm0, wgf[g][2], acc[g]);
#pragma unroll
      for (int g = 0; g < 4; ++g) acc[g] = mfma16(fm1, wgf[g][3], acc[g]);
#pragma unroll
      for (int g = 0; g < 4; ++g) acc[g] = mfma16(fh0, wgf[g][4], acc[g]);
#pragma unroll
      for (int g = 0; g < 4; ++g) acc[g] = mfma16(fh1, wgf[g][5], acc[g]);
#pragma unroll
      for (int g = 0; g < 4; ++g) acc[g] = mfma16(fh2, wgf[g][6], acc[g]);
#pragma unroll
      for (int g = 0; g < 4; ++g) acc[g] = mfma16(fh3, wgf[g][7], acc[g]);
    }
    LGKM_BAR();   // bar B: sCcb/sCh/sCc + staged t+1 ready

    // ---- E: c_c MFMAs + loss shuffle (DS pipe, overlapped) + LSTM + gamma(t+1) ----
    if (w >= 4) {   // issue t+2 loads
      int tq = (t + 2 <= NT - 1) ? t + 2 : NT - 1;
      size_t ga = gbase + (size_t)(tq << 6);
      vx = *(const f32x4*)&values[ga];
      vm = *(const f32x4*)&masks[ga];
      vd = *(const f32x4*)&deltas[ga];
    }
    // est/imp coalesced stores (running pointer)
    *(f32x4*)pout = *(const f32x4*)sOut0;
    pout += 64;
    {
      bf16x8 ac0 = *(const bf16x8*)&sCcb[rA][kg * 8];
      bf16x8 ac1 = *(const bf16x8*)&sCcb[rA][32 + kg * 8];
#pragma unroll
      for (int g = 0; g < 4; ++g) acc[g] = mfma16(ac0, wgf[g][0], acc[g]);
#pragma unroll
      for (int g = 0; g < 4; ++g) acc[g] = mfma16(ac1, wgf[g][1], acc[g]);
    }
    // loss shuffle tree: DS-pipe ops overlap the MFMA/VALU pipes
    if (w < 4) {
#pragma unroll
      for (int off = 32; off > 0; off >>= 1) {
        n1 += __shfl_down(n1, off);
        n2 += __shfl_down(n2, off);
        n3 += __shfl_down(n3, off);
        den += __shfl_down(den, off);
      }
      if (l == 0) {
        f32x4 lv; lv[0] = n1; lv[1] = n2; lv[2] = n3; lv[3] = den;
        *(f32x4*)&sLoss[w][0] = lv;
      }
    }
    // LSTM nonlinearity
#pragma unroll
    for (int i = 0; i < 4; ++i) {
      float ii = sigm(acc[0][i] + bg[0]);
      float ff = sigm(acc[1][i] + bg[1]);
      float g_ = tanh_fast(acc[2][i] + bg[2]);
      float oo = sigm(acc[3][i] + bg[3]);
      float c_ = ff * c_reg[i] + ii * g_;
      c_reg[i] = c_;
      h_reg[i] = oo * tanh_fast(c_);
    }
    if (t < NT - 1) {
      // gamma_h(t+1) from staged d(t+1); decay h into sHb[p^1]
      bf16x8 a0 = *(const bf16x8*)&sDb[p ^ 1][rA][kg * 8];
      bf16x8 a1 = *(const bf16x8*)&sDb[p ^ 1][rA][32 + kg * 8];
      f32x4 ga4 = {0.f, 0.f, 0.f, 0.f};
      ga4 = mfma16(a0, wdhf[0], ga4);
      ga4 = mfma16(a1, wdhf[1], ga4);
#pragma unroll
      for (int i = 0; i < 4; ++i) {
        float g = __expf(-fmaxf(ga4[i] + bdh, 0.f));
        h_reg[i] *= g;
        sHb[p ^ 1][kg * 4 + i][colh] = f2bf(h_reg[i]);
      }
      // gamma_x(t+1) dedup from sDb[p^1]
      int e = tid * 2, rr = e >> 6, f0 = e & 63;
      unsigned int dp = *(const unsigned int*)&sDb[p ^ 1][rr][f0];
      float g0 = __expf(-fmaxf(bf2f(dp & 0xffffu) * sWdxB[f0]     + sWdxB[64 + f0],     0.f));
      float g1 = __expf(-fmaxf(bf2f(dp >> 16)     * sWdxB[f0 + 1] + sWdxB[64 + f0 + 1], 0.f));
      *(unsigned int*)&sGxb[rr][f0] = pk2(g0, g1);
    } else {
#pragma unroll
      for (int i = 0; i < 4; ++i) out_h[(size_t)(b0 + kg * 4 + i) * 128 + colh] = h_reg[i];
    }
    LGKM_BAR();   // bar C: sHb[p^1], sGxb, sLoss ready; step-t LDS reads complete
  }

  // final loss_ws writeback for t = NT-1
  if (tid < 4) {
    float ls = sLoss[0][tid] + sLoss[1][tid] + sLoss[2][tid] + sLoss[3][tid];
    loss_ws[((size_t)(NT - 1) * NBLK + wg) * 4 + tid] = ls;
  }
}

__global__ void rits_loss_kernel(const float* __restrict__ ws, float* __restrict__ out_loss) {
  int tid = threadIdx.x;  // 64 threads; thread t handles step t
  float n1 = 0.f, n2 = 0.f, n3 = 0.f, den = 0.f;
  for (int g = 0; g < NBLK; ++g) {
    const float* p = &ws[((size_t)tid * NBLK + g) * 4];
    n1 += p[0]; n2 += p[1]; n3 += p[2]; den += p[3];
  }
  float lt = (n1 + n2 + n3) / (den + 1e-12f);
#pragma unroll
  for (int off = 32; off > 0; off >>= 1) lt += __shfl_down(lt, off);
  if (tid == 0) out_loss[0] = lt / 192.f;   // / (T * 3)
}

extern "C" void kernel_launch(void* const* d_in, const int* in_sizes, int n_in,
                              void* d_out, int out_size, void* d_ws, size_t ws_size,
                              hipStream_t stream) {
  const float* values = (const float*)d_in[0];
  const float* masks  = (const float*)d_in[1];
  const float* deltas = (const float*)d_in[2];
  const float* W_dh   = (const float*)d_in[3];
  const float* b_dh   = (const float*)d_in[4];
  const float* W_dx   = (const float*)d_in[5];
  const float* b_dx   = (const float*)d_in[6];
  const float* W_hist = (const float*)d_in[7];
  const float* b_hist = (const float*)d_in[8];
  const float* W_feat = (const float*)d_in[9];
  const float* b_feat = (const float*)d_in[10];
  const float* W_comb = (const float*)d_in[11];
  const float* b_comb = (const float*)d_in[12];
  const float* W_ih   = (const float*)d_in[13];
  const float* b_ih   = (const float*)d_in[14];
  const float* W_hh   = (const float*)d_in[15];
  const float* b_hh   = (const float*)d_in[16];

  float* out = (float*)d_out;
  float* out_imp = out;                       // [B,T,F]
  float* out_est = out + (size_t)BTF;         // [B,T,F]
  float* out_h   = out + (size_t)2 * BTF;     // [B,H]
  float* out_ls  = out + (size_t)2 * BTF + (size_t)NB * 128;  // scalar
  float* loss_ws = (float*)d_ws;              // [T][NBLK][4]

  rits_main_kernel<<<NBLK, 512, 0, stream>>>(
      values, masks, deltas, W_dh, b_dh, W_dx, b_dx, W_hist, b_hist,
      W_feat, b_feat, W_comb, b_comb, W_ih, b_ih, W_hh, b_hh,
      out_imp, out_est, out_h, loss_ws);
  rits_loss_kernel<<<1, 64, 0, stream>>>(loss_ws, out_ls);
}